// Round 1
// baseline (486.549 us; speedup 1.0000x reference)
//
#include <hip/hip_runtime.h>

#define NNODES 8192
#define NEDGES 262144
#define FIN 512
#define FHID 512
#define FLAT 128

typedef unsigned short bfu;   // raw bf16 bits
typedef __attribute__((ext_vector_type(8))) short short8;
typedef __attribute__((ext_vector_type(4))) float f32x4;
typedef __attribute__((ext_vector_type(2))) float f32x2;
typedef __attribute__((ext_vector_type(4))) unsigned short us4;

__device__ __forceinline__ float bf2f(unsigned short u) {
    union { unsigned int i; float f; } c; c.i = ((unsigned int)u) << 16; return c.f;
}
__device__ __forceinline__ unsigned short f2bf(float f) {
    union { float f; unsigned int i; } c; c.f = f;
    unsigned int i = c.i;
    unsigned int r = (i + 0x7FFFu + ((i >> 16) & 1u)) >> 16;  // RNE
    return (unsigned short)r;
}

// ---------- graph preprocessing ----------
__global__ void k_zero(int* p, int n) {
    int i = blockIdx.x * blockDim.x + threadIdx.x;
    if (i < n) p[i] = 0;
}

__global__ void k_count(const int* __restrict__ ei, int* __restrict__ deg) {
    int e = blockIdx.x * blockDim.x + threadIdx.x;
    if (e < NEDGES) atomicAdd(&deg[ei[NEDGES + e]], 1);
}

// single block, 256 threads: exclusive scan of deg -> row_start, plus dinv = rsqrt(deg+1)
__global__ void k_scan(const int* __restrict__ deg, int* __restrict__ row_start,
                       float* __restrict__ dinv) {
    __shared__ int part[256];
    int t = threadIdx.x, base = t * 32;
    int s = 0;
    for (int i = 0; i < 32; i++) s += deg[base + i];
    part[t] = s;
    __syncthreads();
    for (int off = 1; off < 256; off <<= 1) {
        int v = (t >= off) ? part[t - off] : 0;
        __syncthreads();
        part[t] += v;
        __syncthreads();
    }
    int run = (t == 0) ? 0 : part[t - 1];
    for (int i = 0; i < 32; i++) {
        int d = deg[base + i];
        row_start[base + i] = run;
        run += d;
        dinv[base + i] = rsqrtf((float)(d + 1));  // +1 self-loop
    }
    if (t == 255) row_start[NNODES] = run;
}

// scatter with fused per-edge weight: wcsr[pos] = dinv[src] (saves the k_wcsr pass)
__global__ void k_scatter(const int* __restrict__ ei, const int* __restrict__ row_start,
                          int* __restrict__ cursor, int* __restrict__ csr,
                          const float* __restrict__ dinv, float* __restrict__ wcsr) {
    int e = blockIdx.x * blockDim.x + threadIdx.x;
    if (e < NEDGES) {
        int src = ei[e];
        int dst = ei[NEDGES + e];
        int p = atomicAdd(&cursor[dst], 1);
        int pos = row_start[dst] + p;
        csr[pos] = src;
        wcsr[pos] = dinv[src];
    }
}

// ---------- x (fp32) -> bf16 ----------
__global__ void k_cvt_x(const float* __restrict__ x, bfu* __restrict__ xb) {
    int i = blockIdx.x * blockDim.x + threadIdx.x;  // over float4s
    const float4 v = ((const float4*)x)[i];
    ushort2 lo = {f2bf(v.x), f2bf(v.y)};
    ushort2 hi = {f2bf(v.z), f2bf(v.w)};
    ((ushort2*)xb)[2 * i] = lo;
    ((ushort2*)xb)[2 * i + 1] = hi;
}

// ---------- weight transposes (fp32 -> bf16), LDS-tiled so both sides coalesce ----------
// Bt1[n*512+k] = W1[k*512+n]
__global__ void k_bt1_t(const float* __restrict__ W, bfu* __restrict__ Bt) {
    __shared__ bfu tile[32][33];   // +1 pad breaks bank aliasing
    int tx = threadIdx.x & 31, ty = threadIdx.x >> 5;   // 32 x 8
    int nb = blockIdx.x & 15, kb = blockIdx.x >> 4;     // 16 x 16 tiles of 32x32
    int n0 = nb * 32, k0 = kb * 32;
#pragma unroll
    for (int i = 0; i < 32; i += 8)
        tile[ty + i][tx] = f2bf(W[(size_t)(k0 + ty + i) * 512 + n0 + tx]);
    __syncthreads();
#pragma unroll
    for (int i = 0; i < 32; i += 8)
        Bt[(size_t)(n0 + ty + i) * 512 + k0 + tx] = tile[tx][ty + i];
}

// Bt2[n*512+k] = (n<128 ? Wmu[k*128+n] : Wlv[k*128+(n-128)]), n in [0,256), k in [0,512)
__global__ void k_bt2_t(const float* __restrict__ Wmu, const float* __restrict__ Wlv,
                        bfu* __restrict__ Bt) {
    __shared__ bfu tile[32][33];
    int tx = threadIdx.x & 31, ty = threadIdx.x >> 5;
    int nb = blockIdx.x & 7, kb = blockIdx.x >> 3;      // 8 x 16 tiles
    int n0 = nb * 32, k0 = kb * 32;
    const float* Wsel = (n0 < 128) ? Wmu : Wlv;
    int noff = (n0 < 128) ? 0 : 128;
#pragma unroll
    for (int i = 0; i < 32; i += 8)
        tile[ty + i][tx] = f2bf(Wsel[(size_t)(k0 + ty + i) * 128 + (n0 + tx - noff)]);
    __syncthreads();
#pragma unroll
    for (int i = 0; i < 32; i += 8)
        Bt[(size_t)(n0 + ty + i) * 512 + k0 + tx] = tile[tx][ty + i];
}

// ---------- generic NT GEMM: C[M,N] = act(A[M,K] @ Bt[N,K]^T), bf16 in, fp32 acc ----------
// wave computes a (16*TM)x(16*TN) tile. Operand-swapped MFMA so acc f32x4 maps to 4
// consecutive output columns -> vector stores (float4 / us4).
// ACT: 0 = none, 2 = sigmoid
// fp32 C path uses non-temporal stores: the 268 MB A_pred stream must not evict the
// 2 MB z-matrix from per-XCD L2 (keeps fragment re-reads L2-resident).
template <int ACT, int TM, int TN, typename CT>
__global__ void k_gemm_nt(const bfu* __restrict__ A, const bfu* __restrict__ Bt,
                          CT* __restrict__ C, int M, int N, int K) {
    int wid  = (blockIdx.x * blockDim.x + threadIdx.x) >> 6;
    int lane = threadIdx.x & 63;
    int l = lane & 15, q = lane >> 4;
    int tn = N / (16 * TN);
    int m0 = (wid / tn) * (16 * TM), n0 = (wid % tn) * (16 * TN);

    f32x4 acc[TM][TN];
#pragma unroll
    for (int a = 0; a < TM; a++)
#pragma unroll
        for (int b = 0; b < TN; b++) acc[a][b] = (f32x4){0.f, 0.f, 0.f, 0.f};

    const bfu* Ap = A + (size_t)(m0 + l) * K + q * 8;
    const bfu* Bp = Bt + (size_t)(n0 + l) * K + q * 8;

    for (int k0 = 0; k0 < K; k0 += 32) {
        short8 av[TM], bv[TN];
#pragma unroll
        for (int mi = 0; mi < TM; mi++)
            av[mi] = *(const short8*)(Ap + (size_t)mi * 16 * K + k0);
#pragma unroll
        for (int ni = 0; ni < TN; ni++)
            bv[ni] = *(const short8*)(Bp + (size_t)ni * 16 * K + k0);
#pragma unroll
        for (int mi = 0; mi < TM; mi++)
#pragma unroll
            for (int ni = 0; ni < TN; ni++)
                acc[mi][ni] = __builtin_amdgcn_mfma_f32_16x16x32_bf16(bv[ni], av[mi],
                                                                     acc[mi][ni], 0, 0, 0);
    }

    // operand-swapped C layout: value acc[mi][ni][r] = C[m0+mi*16+l][n0+ni*16+q*4+r]
#pragma unroll
    for (int mi = 0; mi < TM; mi++) {
        int row = m0 + mi * 16 + l;
#pragma unroll
        for (int ni = 0; ni < TN; ni++) {
            int col = n0 + ni * 16 + q * 4;
            f32x4 v = acc[mi][ni];
            if (ACT == 2) {
#pragma unroll
                for (int r = 0; r < 4; r++)
                    v[r] = __builtin_amdgcn_rcpf(1.0f + __expf(-v[r]));
            }
            if constexpr (sizeof(CT) == 2) {
                us4 o = {f2bf(v[0]), f2bf(v[1]), f2bf(v[2]), f2bf(v[3])};
                *(us4*)(C + (size_t)row * N + col) = o;
            } else {
                __builtin_nontemporal_store(v, (f32x4*)(C + (size_t)row * N + col));
            }
        }
    }
}

// ---------- aggregation, F features, edge loop batched x4 ----------
// out = di * (sum_j w_j * hin[src_j] + di * hin[i])  (self-loop folded in)
template <int F>
__device__ __forceinline__ void agg_core(const bfu* __restrict__ hin,
                                         const int* __restrict__ csr,
                                         const float* __restrict__ wcsr,
                                         int s, int e, int i, int f, float di,
                                         float& a0, float& a1) {
    a0 = 0.f; a1 = 0.f;
    int ed = s;
    for (; ed + 4 <= e; ed += 4) {
        int s0 = csr[ed], s1 = csr[ed + 1], s2 = csr[ed + 2], s3 = csr[ed + 3];
        float w0 = wcsr[ed], w1 = wcsr[ed + 1], w2 = wcsr[ed + 2], w3 = wcsr[ed + 3];
        unsigned int p0 = *(const unsigned int*)(hin + (size_t)s0 * F + f);
        unsigned int p1 = *(const unsigned int*)(hin + (size_t)s1 * F + f);
        unsigned int p2 = *(const unsigned int*)(hin + (size_t)s2 * F + f);
        unsigned int p3 = *(const unsigned int*)(hin + (size_t)s3 * F + f);
        a0 += w0 * bf2f((unsigned short)(p0 & 0xFFFF));
        a1 += w0 * bf2f((unsigned short)(p0 >> 16));
        a0 += w1 * bf2f((unsigned short)(p1 & 0xFFFF));
        a1 += w1 * bf2f((unsigned short)(p1 >> 16));
        a0 += w2 * bf2f((unsigned short)(p2 & 0xFFFF));
        a1 += w2 * bf2f((unsigned short)(p2 >> 16));
        a0 += w3 * bf2f((unsigned short)(p3 & 0xFFFF));
        a1 += w3 * bf2f((unsigned short)(p3 >> 16));
    }
    for (; ed < e; ed++) {
        int src = csr[ed];
        float w = wcsr[ed];
        unsigned int pk = *(const unsigned int*)(hin + (size_t)src * F + f);
        a0 += w * bf2f((unsigned short)(pk & 0xFFFF));
        a1 += w * bf2f((unsigned short)(pk >> 16));
    }
    unsigned int pk = *(const unsigned int*)(hin + (size_t)i * F + f);
    a0 += di * bf2f((unsigned short)(pk & 0xFFFF));
    a1 += di * bf2f((unsigned short)(pk >> 16));
}

// layer 1: h = relu(D^-1/2 A D^-1/2 h0 + b1), F=512, bf16 in/out
__global__ void k_agg1(const bfu* __restrict__ hin, const int* __restrict__ csr,
                       const float* __restrict__ wcsr, const int* __restrict__ rs,
                       const float* __restrict__ dinv, const float* __restrict__ bias,
                       bfu* __restrict__ hout) {
    int i = blockIdx.x;
    int f = threadIdx.x * 2;  // 256 threads x 2 features
    float di = dinv[i];
    float a0, a1;
    agg_core<FHID>(hin, csr, wcsr, rs[i], rs[i + 1], i, f, di, a0, a1);
    float o0 = fmaxf(di * a0 + bias[f], 0.f);
    float o1 = fmaxf(di * a1 + bias[f + 1], 0.f);
    unsigned int outw = (unsigned int)f2bf(o0) | ((unsigned int)f2bf(o1) << 16);
    *(unsigned int*)(hout + (size_t)i * FHID + f) = outw;
}

// layers 2/3 fused: F=256 ([mu | logvar]); fp32 mu/lv/z + bf16 z
// fp32 finals are store-once never-read -> non-temporal (keep h/zb cached instead)
__global__ void k_agg2(const bfu* __restrict__ hin, const int* __restrict__ csr,
                       const float* __restrict__ wcsr, const int* __restrict__ rs,
                       const float* __restrict__ dinv, const float* __restrict__ bmu,
                       const float* __restrict__ blv, float* __restrict__ out_mu,
                       float* __restrict__ out_lv, float* __restrict__ out_z,
                       bfu* __restrict__ ws_z) {
    int i = blockIdx.x;
    int f = threadIdx.x * 2;  // 128 threads x 2 features over 256
    float di = dinv[i];
    float a0, a1;
    agg_core<256>(hin, csr, wcsr, rs[i], rs[i + 1], i, f, di, a0, a1);
    float v0 = di * a0, v1 = di * a1;
    if (f < 128) {
        v0 += bmu[f]; v1 += bmu[f + 1];
        f32x2 fv = {v0, v1};
        __builtin_nontemporal_store(fv, (f32x2*)(out_mu + (size_t)i * FLAT + f));
        __builtin_nontemporal_store(fv, (f32x2*)(out_z + (size_t)i * FLAT + f));  // z = mu
        unsigned int bw = (unsigned int)f2bf(v0) | ((unsigned int)f2bf(v1) << 16);
        *(unsigned int*)(ws_z + (size_t)i * FLAT + f) = bw;   // reused by decode: keep cached
    } else {
        int fl = f - 128;
        v0 += blv[fl]; v1 += blv[fl + 1];
        f32x2 fv = {v0, v1};
        __builtin_nontemporal_store(fv, (f32x2*)(out_lv + (size_t)i * FLAT + fl));
    }
}

extern "C" void kernel_launch(void* const* d_in, const int* in_sizes, int n_in,
                              void* d_out, int out_size, void* d_ws, size_t ws_size,
                              hipStream_t stream) {
    const int*   ei  = (const int*)d_in[0];
    const float* x   = (const float*)d_in[1];
    const float* W1  = (const float*)d_in[2];
    const float* b1  = (const float*)d_in[3];
    const float* Wmu = (const float*)d_in[4];
    const float* bmu = (const float*)d_in[5];
    const float* Wlv = (const float*)d_in[6];
    const float* blv = (const float*)d_in[7];
    float* out = (float*)d_out;

    char* wsb = (char*)d_ws;
    size_t off = 0;
    auto alloc = [&](size_t bytes) -> char* {
        char* p = wsb + off;
        off += (bytes + 255) & ~(size_t)255;
        return p;
    };
    int*   deg       = (int*)alloc(NNODES * 4);
    int*   cursor    = (int*)alloc(NNODES * 4);   // contiguous after deg
    int*   row_start = (int*)alloc((NNODES + 1) * 4);
    float* dinv      = (float*)alloc(NNODES * 4);
    int*   csr       = (int*)alloc(NEDGES * 4);
    float* wcsr      = (float*)alloc(NEDGES * 4);
    bfu*   Bt1       = (bfu*)alloc(512 * 512 * 2);
    bfu*   Bt2       = (bfu*)alloc(256 * 512 * 2);
    bfu*   xb        = (bfu*)alloc((size_t)NNODES * FIN * 2);
    bfu*   h0        = (bfu*)alloc((size_t)NNODES * FHID * 2);
    bfu*   h         = (bfu*)alloc((size_t)NNODES * FHID * 2);
    bfu*   hml       = (bfu*)alloc((size_t)NNODES * 256 * 2);
    bfu*   zb        = (bfu*)alloc((size_t)NNODES * FLAT * 2);

    float* out_mu = out + (size_t)NNODES * NNODES;
    float* out_lv = out_mu + (size_t)NNODES * FLAT;
    float* out_z  = out_lv + (size_t)NNODES * FLAT;

    // graph prep
    k_zero<<<(2 * NNODES + 255) / 256, 256, 0, stream>>>(deg, 2 * NNODES);  // deg + cursor
    k_count<<<NEDGES / 256, 256, 0, stream>>>(ei, deg);
    k_scan<<<1, 256, 0, stream>>>(deg, row_start, dinv);
    k_scatter<<<NEDGES / 256, 256, 0, stream>>>(ei, row_start, cursor, csr, dinv, wcsr);
    k_bt1_t<<<256, 256, 0, stream>>>(W1, Bt1);
    k_bt2_t<<<128, 256, 0, stream>>>(Wmu, Wlv, Bt2);
    k_cvt_x<<<(NNODES * FIN / 4) / 256, 256, 0, stream>>>(x, xb);

    // layer 1: h0 = x @ W1 (64x32/wave -> 2048 waves) ; h = relu(agg(h0) + b1)
    k_gemm_nt<0, 4, 2, bfu><<<(8192 / 64) * (512 / 32) / 4, 256, 0, stream>>>(
        xb, Bt1, h0, 8192, 512, 512);
    k_agg1<<<NNODES, 256, 0, stream>>>(h0, csr, wcsr, row_start, dinv, b1, h);

    // layers 2+3 fused: hml = h @ [Wmu|Wlv] (32x32/wave -> 2048 waves)
    k_gemm_nt<0, 2, 2, bfu><<<(8192 / 32) * (256 / 32) / 4, 256, 0, stream>>>(
        h, Bt2, hml, 8192, 256, 512);
    k_agg2<<<NNODES, 128, 0, stream>>>(hml, csr, wcsr, row_start, dinv, bmu, blv,
                                       out_mu, out_lv, out_z, zb);

    // decode: A_pred = sigmoid(z @ z^T), fp32 out, 64x64/wave -> 16384 waves
    k_gemm_nt<2, 4, 4, float><<<(8192 / 64) * (8192 / 64) / 4, 256, 0, stream>>>(
        zb, zb, out, 8192, 8192, 128);
}

// Round 2
// 450.938 us; speedup vs baseline: 1.0790x; 1.0790x over previous
//
#include <hip/hip_runtime.h>
#include <math.h>

#define NNODES 8192
#define NEDGES 262144
#define FIN 512
#define FHID 512
#define FLAT 128

typedef unsigned short bfu;   // raw bf16 bits
typedef __attribute__((ext_vector_type(8))) short short8;
typedef __attribute__((ext_vector_type(4))) float f32x4;
typedef __attribute__((ext_vector_type(2))) float f32x2;
typedef __attribute__((ext_vector_type(4))) unsigned short us4;

__device__ __forceinline__ float bf2f(unsigned short u) {
    union { unsigned int i; float f; } c; c.i = ((unsigned int)u) << 16; return c.f;
}
__device__ __forceinline__ unsigned short f2bf(float f) {
    union { float f; unsigned int i; } c; c.f = f;
    unsigned int i = c.i;
    unsigned int r = (i + 0x7FFFu + ((i >> 16) & 1u)) >> 16;  // RNE
    return (unsigned short)r;
}

// ---------- graph preprocessing ----------
__global__ void k_zero(int* p, int n) {
    int i = blockIdx.x * blockDim.x + threadIdx.x;
    if (i < n) p[i] = 0;
}

__global__ void k_count(const int* __restrict__ ei, int* __restrict__ deg) {
    int e = blockIdx.x * blockDim.x + threadIdx.x;
    if (e < NEDGES) atomicAdd(&deg[ei[NEDGES + e]], 1);
}

// single block, 256 threads: exclusive scan of deg -> row_start, plus dinv = rsqrt(deg+1)
__global__ void k_scan(const int* __restrict__ deg, int* __restrict__ row_start,
                       float* __restrict__ dinv) {
    __shared__ int part[256];
    int t = threadIdx.x, base = t * 32;
    int s = 0;
    for (int i = 0; i < 32; i++) s += deg[base + i];
    part[t] = s;
    __syncthreads();
    for (int off = 1; off < 256; off <<= 1) {
        int v = (t >= off) ? part[t - off] : 0;
        __syncthreads();
        part[t] += v;
        __syncthreads();
    }
    int run = (t == 0) ? 0 : part[t - 1];
    for (int i = 0; i < 32; i++) {
        int d = deg[base + i];
        row_start[base + i] = run;
        run += d;
        dinv[base + i] = rsqrtf((float)(d + 1));  // +1 self-loop
    }
    if (t == 255) row_start[NNODES] = run;
}

// scatter with fused per-edge weight: wcsr[pos] = dinv[src]
__global__ void k_scatter(const int* __restrict__ ei, const int* __restrict__ row_start,
                          int* __restrict__ cursor, int* __restrict__ csr,
                          const float* __restrict__ dinv, float* __restrict__ wcsr) {
    int e = blockIdx.x * blockDim.x + threadIdx.x;
    if (e < NEDGES) {
        int src = ei[e];
        int dst = ei[NEDGES + e];
        int p = atomicAdd(&cursor[dst], 1);
        int pos = row_start[dst] + p;
        csr[pos] = src;
        wcsr[pos] = dinv[src];
    }
}

// ---------- fused constant prep: weight transposes (fp32->bf16, LDS-tiled) + x->bf16 ----------
// blocks [0,256): Bt1[n*512+k] = W1[k*512+n]           (16x16 tiles of 32x32)
// blocks [256,384): Bt2[n*512+k] = [Wmu|Wlv]^T          (8x16 tiles)
// blocks [384,4480): xb = bf16(x)                       (float4-granular)
__global__ void k_prep_const(const float* __restrict__ W1, const float* __restrict__ Wmu,
                             const float* __restrict__ Wlv, const float* __restrict__ x,
                             bfu* __restrict__ Bt1, bfu* __restrict__ Bt2,
                             bfu* __restrict__ xb) {
    __shared__ bfu tile[32][33];   // +1 pad breaks bank aliasing
    int b = blockIdx.x;
    if (b < 256) {
        int tx = threadIdx.x & 31, ty = threadIdx.x >> 5;   // 32 x 8
        int nb = b & 15, kb = b >> 4;
        int n0 = nb * 32, k0 = kb * 32;
#pragma unroll
        for (int i = 0; i < 32; i += 8)
            tile[ty + i][tx] = f2bf(W1[(size_t)(k0 + ty + i) * 512 + n0 + tx]);
        __syncthreads();
#pragma unroll
        for (int i = 0; i < 32; i += 8)
            Bt1[(size_t)(n0 + ty + i) * 512 + k0 + tx] = tile[tx][ty + i];
    } else if (b < 384) {
        int bb = b - 256;
        int tx = threadIdx.x & 31, ty = threadIdx.x >> 5;
        int nb = bb & 7, kb = bb >> 3;
        int n0 = nb * 32, k0 = kb * 32;
        const float* Wsel = (n0 < 128) ? Wmu : Wlv;
        int noff = (n0 < 128) ? 0 : 128;
#pragma unroll
        for (int i = 0; i < 32; i += 8)
            tile[ty + i][tx] = f2bf(Wsel[(size_t)(k0 + ty + i) * 128 + (n0 + tx - noff)]);
        __syncthreads();
#pragma unroll
        for (int i = 0; i < 32; i += 8)
            Bt2[(size_t)(n0 + ty + i) * 512 + k0 + tx] = tile[tx][ty + i];
    } else {
        int i = (b - 384) * 256 + threadIdx.x;  // over float4s
        const float4 v = ((const float4*)x)[i];
        ushort2 lo = {f2bf(v.x), f2bf(v.y)};
        ushort2 hi = {f2bf(v.z), f2bf(v.w)};
        ((ushort2*)xb)[2 * i] = lo;
        ((ushort2*)xb)[2 * i + 1] = hi;
    }
}

// ---------- generic NT GEMM: C[M,N] = A[M,K] @ Bt[N,K]^T, bf16 in/out, fp32 acc ----------
// wave computes a (16*TM)x(16*TN) tile; operand-swapped MFMA -> acc f32x4 = 4 consecutive cols.
template <int TM, int TN>
__global__ void k_gemm_nt(const bfu* __restrict__ A, const bfu* __restrict__ Bt,
                          bfu* __restrict__ C, int M, int N, int K) {
    int wid  = (blockIdx.x * blockDim.x + threadIdx.x) >> 6;
    int lane = threadIdx.x & 63;
    int l = lane & 15, q = lane >> 4;
    int tn = N / (16 * TN);
    int m0 = (wid / tn) * (16 * TM), n0 = (wid % tn) * (16 * TN);

    f32x4 acc[TM][TN];
#pragma unroll
    for (int a = 0; a < TM; a++)
#pragma unroll
        for (int b = 0; b < TN; b++) acc[a][b] = (f32x4){0.f, 0.f, 0.f, 0.f};

    const bfu* Ap = A + (size_t)(m0 + l) * K + q * 8;
    const bfu* Bp = Bt + (size_t)(n0 + l) * K + q * 8;

    for (int k0 = 0; k0 < K; k0 += 32) {
        short8 av[TM], bv[TN];
#pragma unroll
        for (int mi = 0; mi < TM; mi++)
            av[mi] = *(const short8*)(Ap + (size_t)mi * 16 * K + k0);
#pragma unroll
        for (int ni = 0; ni < TN; ni++)
            bv[ni] = *(const short8*)(Bp + (size_t)ni * 16 * K + k0);
#pragma unroll
        for (int mi = 0; mi < TM; mi++)
#pragma unroll
            for (int ni = 0; ni < TN; ni++)
                acc[mi][ni] = __builtin_amdgcn_mfma_f32_16x16x32_bf16(bv[ni], av[mi],
                                                                     acc[mi][ni], 0, 0, 0);
    }

    // acc[mi][ni][r] = C[m0+mi*16+l][n0+ni*16+q*4+r]
#pragma unroll
    for (int mi = 0; mi < TM; mi++) {
        int row = m0 + mi * 16 + l;
#pragma unroll
        for (int ni = 0; ni < TN; ni++) {
            int col = n0 + ni * 16 + q * 4;
            f32x4 v = acc[mi][ni];
            us4 o = {f2bf(v[0]), f2bf(v[1]), f2bf(v[2]), f2bf(v[3])};
            *(us4*)(C + (size_t)row * N + col) = o;
        }
    }
}

// ---------- symmetric decode: A_pred = sigmoid(z @ z^T), upper-triangle tiles only ----------
// 64x64 tile per wave over tile-pairs (ti<=tj); off-diagonal tiles mirrored via LDS
// chunk-transpose (16x64 fp32, stride-68 pad, double-buffered by ni parity).
// Mirror values are bit-identical (same fp32 dot, same k-order; multiply commutes).
__global__ __launch_bounds__(256) void k_decode_sym(const bfu* __restrict__ Z,
                                                    float* __restrict__ C) {
    __shared__ float ldsT[4][2][16][68];
    int wid  = (blockIdx.x * blockDim.x + threadIdx.x) >> 6;
    int wv   = threadIdx.x >> 6;
    int lane = threadIdx.x & 63;
    int l = lane & 15, q = lane >> 4;

    // triangular map: wid in [0, 8256) -> (ti, tj), ti <= tj < 128
    // off(t) = t*(257-t)/2
    int idx = wid;
    int ti = (int)((257.0 - sqrt(66049.0 - 8.0 * (double)idx)) * 0.5);
    if (ti > 127) ti = 127;
    if (ti < 0) ti = 0;
    while (ti > 0 && (ti * (257 - ti)) / 2 > idx) ti--;
    while (ti < 127 && ((ti + 1) * (256 - ti)) / 2 <= idx) ti++;
    int tj = ti + (idx - (ti * (257 - ti)) / 2);
    int m0 = ti * 64, n0 = tj * 64;

    f32x4 acc[4][4];
#pragma unroll
    for (int a = 0; a < 4; a++)
#pragma unroll
        for (int b = 0; b < 4; b++) acc[a][b] = (f32x4){0.f, 0.f, 0.f, 0.f};

    const bfu* Ap = Z + (size_t)(m0 + l) * 128 + q * 8;
    const bfu* Bp = Z + (size_t)(n0 + l) * 128 + q * 8;

#pragma unroll
    for (int k0 = 0; k0 < 128; k0 += 32) {
        short8 av[4], bv[4];
#pragma unroll
        for (int mi = 0; mi < 4; mi++)
            av[mi] = *(const short8*)(Ap + (size_t)mi * 16 * 128 + k0);
#pragma unroll
        for (int ni = 0; ni < 4; ni++)
            bv[ni] = *(const short8*)(Bp + (size_t)ni * 16 * 128 + k0);
#pragma unroll
        for (int mi = 0; mi < 4; mi++)
#pragma unroll
            for (int ni = 0; ni < 4; ni++)
                acc[mi][ni] = __builtin_amdgcn_mfma_f32_16x16x32_bf16(bv[ni], av[mi],
                                                                     acc[mi][ni], 0, 0, 0);
    }

    // sigmoid in place (identical op sequence to previous rounds -> bit-identical)
#pragma unroll
    for (int mi = 0; mi < 4; mi++)
#pragma unroll
        for (int ni = 0; ni < 4; ni++)
#pragma unroll
            for (int r = 0; r < 4; r++)
                acc[mi][ni][r] = __builtin_amdgcn_rcpf(1.0f + __expf(-acc[mi][ni][r]));

    // normal (upper) tile store: coalesced f32x4 nt-stores
#pragma unroll
    for (int mi = 0; mi < 4; mi++) {
        int row = m0 + mi * 16 + l;
#pragma unroll
        for (int ni = 0; ni < 4; ni++) {
            int col = n0 + ni * 16 + q * 4;
            __builtin_nontemporal_store(acc[mi][ni], (f32x4*)(C + (size_t)row * 8192 + col));
        }
    }

    // mirror (lower) tile via LDS chunk-transpose
    if (ti != tj) {
#pragma unroll
        for (int ni = 0; ni < 4; ni++) {
            int p = ni & 1;
            // write: value at (row m0+mi*16+l, col n0+ni*16+q*4+r) -> mirror row q*4+r, col mi*16+l
#pragma unroll
            for (int mi = 0; mi < 4; mi++)
#pragma unroll
                for (int r = 0; r < 4; r++)
                    ldsT[wv][p][q * 4 + r][mi * 16 + l] = acc[mi][ni][r];
            asm volatile("s_waitcnt lgkmcnt(0)" ::: "memory");
            // read row j, 64 consecutive cols -> coalesced 256B store per row
#pragma unroll
            for (int j = 0; j < 16; j++) {
                float v = ldsT[wv][p][j][lane];
                __builtin_nontemporal_store(
                    v, C + (size_t)(n0 + ni * 16 + j) * 8192 + m0 + lane);
            }
        }
    }
}

// ---------- aggregation, F features, edge loop batched x4 ----------
template <int F>
__device__ __forceinline__ void agg_core(const bfu* __restrict__ hin,
                                         const int* __restrict__ csr,
                                         const float* __restrict__ wcsr,
                                         int s, int e, int i, int f, float di,
                                         float& a0, float& a1) {
    a0 = 0.f; a1 = 0.f;
    int ed = s;
    for (; ed + 4 <= e; ed += 4) {
        int s0 = csr[ed], s1 = csr[ed + 1], s2 = csr[ed + 2], s3 = csr[ed + 3];
        float w0 = wcsr[ed], w1 = wcsr[ed + 1], w2 = wcsr[ed + 2], w3 = wcsr[ed + 3];
        unsigned int p0 = *(const unsigned int*)(hin + (size_t)s0 * F + f);
        unsigned int p1 = *(const unsigned int*)(hin + (size_t)s1 * F + f);
        unsigned int p2 = *(const unsigned int*)(hin + (size_t)s2 * F + f);
        unsigned int p3 = *(const unsigned int*)(hin + (size_t)s3 * F + f);
        a0 += w0 * bf2f((unsigned short)(p0 & 0xFFFF));
        a1 += w0 * bf2f((unsigned short)(p0 >> 16));
        a0 += w1 * bf2f((unsigned short)(p1 & 0xFFFF));
        a1 += w1 * bf2f((unsigned short)(p1 >> 16));
        a0 += w2 * bf2f((unsigned short)(p2 & 0xFFFF));
        a1 += w2 * bf2f((unsigned short)(p2 >> 16));
        a0 += w3 * bf2f((unsigned short)(p3 & 0xFFFF));
        a1 += w3 * bf2f((unsigned short)(p3 >> 16));
    }
    for (; ed < e; ed++) {
        int src = csr[ed];
        float w = wcsr[ed];
        unsigned int pk = *(const unsigned int*)(hin + (size_t)src * F + f);
        a0 += w * bf2f((unsigned short)(pk & 0xFFFF));
        a1 += w * bf2f((unsigned short)(pk >> 16));
    }
    unsigned int pk = *(const unsigned int*)(hin + (size_t)i * F + f);
    a0 += di * bf2f((unsigned short)(pk & 0xFFFF));
    a1 += di * bf2f((unsigned short)(pk >> 16));
}

// layer 1: h = relu(D^-1/2 A D^-1/2 h0 + b1), F=512, bf16 in/out
__global__ void k_agg1(const bfu* __restrict__ hin, const int* __restrict__ csr,
                       const float* __restrict__ wcsr, const int* __restrict__ rs,
                       const float* __restrict__ dinv, const float* __restrict__ bias,
                       bfu* __restrict__ hout) {
    int i = blockIdx.x;
    int f = threadIdx.x * 2;  // 256 threads x 2 features
    float di = dinv[i];
    float a0, a1;
    agg_core<FHID>(hin, csr, wcsr, rs[i], rs[i + 1], i, f, di, a0, a1);
    float o0 = fmaxf(di * a0 + bias[f], 0.f);
    float o1 = fmaxf(di * a1 + bias[f + 1], 0.f);
    unsigned int outw = (unsigned int)f2bf(o0) | ((unsigned int)f2bf(o1) << 16);
    *(unsigned int*)(hout + (size_t)i * FHID + f) = outw;
}

// layers 2/3 fused: F=256 ([mu | logvar]); fp32 mu/lv/z + bf16 z
__global__ void k_agg2(const bfu* __restrict__ hin, const int* __restrict__ csr,
                       const float* __restrict__ wcsr, const int* __restrict__ rs,
                       const float* __restrict__ dinv, const float* __restrict__ bmu,
                       const float* __restrict__ blv, float* __restrict__ out_mu,
                       float* __restrict__ out_lv, float* __restrict__ out_z,
                       bfu* __restrict__ ws_z) {
    int i = blockIdx.x;
    int f = threadIdx.x * 2;  // 128 threads x 2 features over 256
    float di = dinv[i];
    float a0, a1;
    agg_core<256>(hin, csr, wcsr, rs[i], rs[i + 1], i, f, di, a0, a1);
    float v0 = di * a0, v1 = di * a1;
    if (f < 128) {
        v0 += bmu[f]; v1 += bmu[f + 1];
        f32x2 fv = {v0, v1};
        __builtin_nontemporal_store(fv, (f32x2*)(out_mu + (size_t)i * FLAT + f));
        __builtin_nontemporal_store(fv, (f32x2*)(out_z + (size_t)i * FLAT + f));  // z = mu
        unsigned int bw = (unsigned int)f2bf(v0) | ((unsigned int)f2bf(v1) << 16);
        *(unsigned int*)(ws_z + (size_t)i * FLAT + f) = bw;   // reused by decode: keep cached
    } else {
        int fl = f - 128;
        v0 += blv[fl]; v1 += blv[fl + 1];
        f32x2 fv = {v0, v1};
        __builtin_nontemporal_store(fv, (f32x2*)(out_lv + (size_t)i * FLAT + fl));
    }
}

extern "C" void kernel_launch(void* const* d_in, const int* in_sizes, int n_in,
                              void* d_out, int out_size, void* d_ws, size_t ws_size,
                              hipStream_t stream) {
    const int*   ei  = (const int*)d_in[0];
    const float* x   = (const float*)d_in[1];
    const float* W1  = (const float*)d_in[2];
    const float* b1  = (const float*)d_in[3];
    const float* Wmu = (const float*)d_in[4];
    const float* bmu = (const float*)d_in[5];
    const float* Wlv = (const float*)d_in[6];
    const float* blv = (const float*)d_in[7];
    float* out = (float*)d_out;

    char* wsb = (char*)d_ws;
    size_t off = 0;
    auto alloc = [&](size_t bytes) -> char* {
        char* p = wsb + off;
        off += (bytes + 255) & ~(size_t)255;
        return p;
    };
    int*   deg       = (int*)alloc(NNODES * 4);
    int*   cursor    = (int*)alloc(NNODES * 4);   // contiguous after deg
    int*   row_start = (int*)alloc((NNODES + 1) * 4);
    float* dinv      = (float*)alloc(NNODES * 4);
    int*   csr       = (int*)alloc(NEDGES * 4);
    float* wcsr      = (float*)alloc(NEDGES * 4);
    bfu*   Bt1       = (bfu*)alloc(512 * 512 * 2);
    bfu*   Bt2       = (bfu*)alloc(256 * 512 * 2);
    bfu*   xb        = (bfu*)alloc((size_t)NNODES * FIN * 2);
    bfu*   h0        = (bfu*)alloc((size_t)NNODES * FHID * 2);
    bfu*   h         = (bfu*)alloc((size_t)NNODES * FHID * 2);
    bfu*   hml       = (bfu*)alloc((size_t)NNODES * 256 * 2);
    bfu*   zb        = (bfu*)alloc((size_t)NNODES * FLAT * 2);

    float* out_mu = out + (size_t)NNODES * NNODES;
    float* out_lv = out_mu + (size_t)NNODES * FLAT;
    float* out_z  = out_lv + (size_t)NNODES * FLAT;

    // graph prep
    k_zero<<<(2 * NNODES + 255) / 256, 256, 0, stream>>>(deg, 2 * NNODES);  // deg + cursor
    k_count<<<NEDGES / 256, 256, 0, stream>>>(ei, deg);
    k_scan<<<1, 256, 0, stream>>>(deg, row_start, dinv);
    k_scatter<<<NEDGES / 256, 256, 0, stream>>>(ei, row_start, cursor, csr, dinv, wcsr);
    k_prep_const<<<256 + 128 + 4096, 256, 0, stream>>>(W1, Wmu, Wlv, x, Bt1, Bt2, xb);

    // layer 1: h0 = x @ W1 (64x32/wave -> 2048 waves) ; h = relu(agg(h0) + b1)
    k_gemm_nt<4, 2><<<(8192 / 64) * (512 / 32) / 4, 256, 0, stream>>>(
        xb, Bt1, h0, 8192, 512, 512);
    k_agg1<<<NNODES, 256, 0, stream>>>(h0, csr, wcsr, row_start, dinv, b1, h);

    // layers 2+3 fused: hml = h @ [Wmu|Wlv] (32x32/wave -> 2048 waves)
    k_gemm_nt<2, 2><<<(8192 / 32) * (256 / 32) / 4, 256, 0, stream>>>(
        h, Bt2, hml, 8192, 256, 512);
    k_agg2<<<NNODES, 128, 0, stream>>>(hml, csr, wcsr, row_start, dinv, bmu, blv,
                                       out_mu, out_lv, out_z, zb);

    // decode: upper-triangle tile-pairs only (8256 wave-tiles / 4 waves per block)
    k_decode_sym<<<8256 / 4, 256, 0, stream>>>(zb, out);
}

// Round 3
// 448.635 us; speedup vs baseline: 1.0845x; 1.0051x over previous
//
#include <hip/hip_runtime.h>
#include <math.h>

#define NNODES 8192
#define NEDGES 262144
#define FIN 512
#define FHID 512
#define FLAT 128

typedef unsigned short bfu;   // raw bf16 bits
typedef __attribute__((ext_vector_type(8))) short short8;
typedef __attribute__((ext_vector_type(4))) float f32x4;
typedef __attribute__((ext_vector_type(2))) float f32x2;
typedef __attribute__((ext_vector_type(4))) unsigned short us4;

__device__ __forceinline__ float bf2f(unsigned short u) {
    union { unsigned int i; float f; } c; c.i = ((unsigned int)u) << 16; return c.f;
}
__device__ __forceinline__ unsigned short f2bf(float f) {
    union { float f; unsigned int i; } c; c.f = f;
    unsigned int i = c.i;
    unsigned int r = (i + 0x7FFFu + ((i >> 16) & 1u)) >> 16;  // RNE
    return (unsigned short)r;
}

// accumulate 8 bf16 features (one uint4) with weight w
__device__ __forceinline__ void acc8(float* acc, uint4 v, float w) {
    acc[0] += w * bf2f((unsigned short)(v.x & 0xFFFF));
    acc[1] += w * bf2f((unsigned short)(v.x >> 16));
    acc[2] += w * bf2f((unsigned short)(v.y & 0xFFFF));
    acc[3] += w * bf2f((unsigned short)(v.y >> 16));
    acc[4] += w * bf2f((unsigned short)(v.z & 0xFFFF));
    acc[5] += w * bf2f((unsigned short)(v.z >> 16));
    acc[6] += w * bf2f((unsigned short)(v.w & 0xFFFF));
    acc[7] += w * bf2f((unsigned short)(v.w >> 16));
}
// accumulate 4 bf16 features (one uint2) with weight w
__device__ __forceinline__ void acc4(float* acc, uint2 v, float w) {
    acc[0] += w * bf2f((unsigned short)(v.x & 0xFFFF));
    acc[1] += w * bf2f((unsigned short)(v.x >> 16));
    acc[2] += w * bf2f((unsigned short)(v.y & 0xFFFF));
    acc[3] += w * bf2f((unsigned short)(v.y >> 16));
}

// ---------- graph preprocessing ----------
__global__ void k_zero(int* p, int n) {
    int i = blockIdx.x * blockDim.x + threadIdx.x;
    if (i < n) p[i] = 0;
}

__global__ void k_count(const int* __restrict__ ei, int* __restrict__ deg) {
    int e = blockIdx.x * blockDim.x + threadIdx.x;
    if (e < NEDGES) atomicAdd(&deg[ei[NEDGES + e]], 1);
}

// single block, 256 threads: exclusive scan of deg -> row_start, plus dinv = rsqrt(deg+1)
__global__ void k_scan(const int* __restrict__ deg, int* __restrict__ row_start,
                       float* __restrict__ dinv) {
    __shared__ int part[256];
    int t = threadIdx.x, base = t * 32;
    int s = 0;
    for (int i = 0; i < 32; i++) s += deg[base + i];
    part[t] = s;
    __syncthreads();
    for (int off = 1; off < 256; off <<= 1) {
        int v = (t >= off) ? part[t - off] : 0;
        __syncthreads();
        part[t] += v;
        __syncthreads();
    }
    int run = (t == 0) ? 0 : part[t - 1];
    for (int i = 0; i < 32; i++) {
        int d = deg[base + i];
        row_start[base + i] = run;
        run += d;
        dinv[base + i] = rsqrtf((float)(d + 1));  // +1 self-loop
    }
    if (t == 255) row_start[NNODES] = run;
}

// ---------- fused: edge scatter (packed {src,w} pairs) + weight transposes + x->bf16 ----------
// blocks [0,1024): scatter; [1024,1280): Bt1 tiles; [1280,1408): Bt2 tiles; [1408,5504): cvt x
__global__ void k_scatter_prep(const int* __restrict__ ei, const int* __restrict__ row_start,
                               int* __restrict__ cursor, int2* __restrict__ ep,
                               const float* __restrict__ dinv,
                               const float* __restrict__ W1, const float* __restrict__ Wmu,
                               const float* __restrict__ Wlv, const float* __restrict__ x,
                               bfu* __restrict__ Bt1, bfu* __restrict__ Bt2,
                               bfu* __restrict__ xb) {
    __shared__ bfu tile[32][33];   // +1 pad breaks bank aliasing
    int b = blockIdx.x;
    if (b < 1024) {
        int e = b * 256 + threadIdx.x;
        int src = ei[e];
        int dst = ei[NEDGES + e];
        int p = atomicAdd(&cursor[dst], 1);
        int2 pr;
        pr.x = src;
        pr.y = __float_as_int(dinv[src]);
        ep[row_start[dst] + p] = pr;
    } else if (b < 1280) {
        int bb = b - 1024;
        int tx = threadIdx.x & 31, ty = threadIdx.x >> 5;   // 32 x 8
        int nb = bb & 15, kb = bb >> 4;
        int n0 = nb * 32, k0 = kb * 32;
#pragma unroll
        for (int i = 0; i < 32; i += 8)
            tile[ty + i][tx] = f2bf(W1[(size_t)(k0 + ty + i) * 512 + n0 + tx]);
        __syncthreads();
#pragma unroll
        for (int i = 0; i < 32; i += 8)
            Bt1[(size_t)(n0 + ty + i) * 512 + k0 + tx] = tile[tx][ty + i];
    } else if (b < 1408) {
        int bb = b - 1280;
        int tx = threadIdx.x & 31, ty = threadIdx.x >> 5;
        int nb = bb & 7, kb = bb >> 3;
        int n0 = nb * 32, k0 = kb * 32;
        const float* Wsel = (n0 < 128) ? Wmu : Wlv;
        int noff = (n0 < 128) ? 0 : 128;
#pragma unroll
        for (int i = 0; i < 32; i += 8)
            tile[ty + i][tx] = f2bf(Wsel[(size_t)(k0 + ty + i) * 128 + (n0 + tx - noff)]);
        __syncthreads();
#pragma unroll
        for (int i = 0; i < 32; i += 8)
            Bt2[(size_t)(n0 + ty + i) * 512 + k0 + tx] = tile[tx][ty + i];
    } else {
        int i = (b - 1408) * 256 + threadIdx.x;  // over float4s
        const float4 v = ((const float4*)x)[i];
        ushort2 lo = {f2bf(v.x), f2bf(v.y)};
        ushort2 hi = {f2bf(v.z), f2bf(v.w)};
        ((ushort2*)xb)[2 * i] = lo;
        ((ushort2*)xb)[2 * i + 1] = hi;
    }
}

// ---------- generic NT GEMM: C[M,N] = A[M,K] @ Bt[N,K]^T, bf16 in/out, fp32 acc ----------
template <int TM, int TN>
__global__ void k_gemm_nt(const bfu* __restrict__ A, const bfu* __restrict__ Bt,
                          bfu* __restrict__ C, int M, int N, int K) {
    int wid  = (blockIdx.x * blockDim.x + threadIdx.x) >> 6;
    int lane = threadIdx.x & 63;
    int l = lane & 15, q = lane >> 4;
    int tn = N / (16 * TN);
    int m0 = (wid / tn) * (16 * TM), n0 = (wid % tn) * (16 * TN);

    f32x4 acc[TM][TN];
#pragma unroll
    for (int a = 0; a < TM; a++)
#pragma unroll
        for (int b = 0; b < TN; b++) acc[a][b] = (f32x4){0.f, 0.f, 0.f, 0.f};

    const bfu* Ap = A + (size_t)(m0 + l) * K + q * 8;
    const bfu* Bp = Bt + (size_t)(n0 + l) * K + q * 8;

    for (int k0 = 0; k0 < K; k0 += 32) {
        short8 av[TM], bv[TN];
#pragma unroll
        for (int mi = 0; mi < TM; mi++)
            av[mi] = *(const short8*)(Ap + (size_t)mi * 16 * K + k0);
#pragma unroll
        for (int ni = 0; ni < TN; ni++)
            bv[ni] = *(const short8*)(Bp + (size_t)ni * 16 * K + k0);
#pragma unroll
        for (int mi = 0; mi < TM; mi++)
#pragma unroll
            for (int ni = 0; ni < TN; ni++)
                acc[mi][ni] = __builtin_amdgcn_mfma_f32_16x16x32_bf16(bv[ni], av[mi],
                                                                     acc[mi][ni], 0, 0, 0);
    }

    // acc[mi][ni][r] = C[m0+mi*16+l][n0+ni*16+q*4+r]
#pragma unroll
    for (int mi = 0; mi < TM; mi++) {
        int row = m0 + mi * 16 + l;
#pragma unroll
        for (int ni = 0; ni < TN; ni++) {
            int col = n0 + ni * 16 + q * 4;
            f32x4 v = acc[mi][ni];
            us4 o = {f2bf(v[0]), f2bf(v[1]), f2bf(v[2]), f2bf(v[3])};
            *(us4*)(C + (size_t)row * N + col) = o;
        }
    }
}

// ---------- symmetric decode: A_pred = sigmoid(z @ z^T), upper-triangle tiles only ----------
__global__ __launch_bounds__(256) void k_decode_sym(const bfu* __restrict__ Z,
                                                    float* __restrict__ C) {
    __shared__ float ldsT[4][2][16][68];
    int wid  = (blockIdx.x * blockDim.x + threadIdx.x) >> 6;
    int wv   = threadIdx.x >> 6;
    int lane = threadIdx.x & 63;
    int l = lane & 15, q = lane >> 4;

    // triangular map: wid in [0, 8256) -> (ti, tj), ti <= tj < 128; off(t) = t*(257-t)/2
    int idx = wid;
    int ti = (int)((257.0 - sqrt(66049.0 - 8.0 * (double)idx)) * 0.5);
    if (ti > 127) ti = 127;
    if (ti < 0) ti = 0;
    while (ti > 0 && (ti * (257 - ti)) / 2 > idx) ti--;
    while (ti < 127 && ((ti + 1) * (256 - ti)) / 2 <= idx) ti++;
    int tj = ti + (idx - (ti * (257 - ti)) / 2);
    int m0 = ti * 64, n0 = tj * 64;

    f32x4 acc[4][4];
#pragma unroll
    for (int a = 0; a < 4; a++)
#pragma unroll
        for (int b = 0; b < 4; b++) acc[a][b] = (f32x4){0.f, 0.f, 0.f, 0.f};

    const bfu* Ap = Z + (size_t)(m0 + l) * 128 + q * 8;
    const bfu* Bp = Z + (size_t)(n0 + l) * 128 + q * 8;

#pragma unroll
    for (int k0 = 0; k0 < 128; k0 += 32) {
        short8 av[4], bv[4];
#pragma unroll
        for (int mi = 0; mi < 4; mi++)
            av[mi] = *(const short8*)(Ap + (size_t)mi * 16 * 128 + k0);
#pragma unroll
        for (int ni = 0; ni < 4; ni++)
            bv[ni] = *(const short8*)(Bp + (size_t)ni * 16 * 128 + k0);
#pragma unroll
        for (int mi = 0; mi < 4; mi++)
#pragma unroll
            for (int ni = 0; ni < 4; ni++)
                acc[mi][ni] = __builtin_amdgcn_mfma_f32_16x16x32_bf16(bv[ni], av[mi],
                                                                     acc[mi][ni], 0, 0, 0);
    }

    // sigmoid in place (identical op sequence -> bit-identical)
#pragma unroll
    for (int mi = 0; mi < 4; mi++)
#pragma unroll
        for (int ni = 0; ni < 4; ni++)
#pragma unroll
            for (int r = 0; r < 4; r++)
                acc[mi][ni][r] = __builtin_amdgcn_rcpf(1.0f + __expf(-acc[mi][ni][r]));

    // upper tile: coalesced f32x4 nt-stores
#pragma unroll
    for (int mi = 0; mi < 4; mi++) {
        int row = m0 + mi * 16 + l;
#pragma unroll
        for (int ni = 0; ni < 4; ni++) {
            int col = n0 + ni * 16 + q * 4;
            __builtin_nontemporal_store(acc[mi][ni], (f32x4*)(C + (size_t)row * 8192 + col));
        }
    }

    // mirror (lower) tile via LDS chunk-transpose; f32x4-wide stores
    if (ti != tj) {
#pragma unroll
        for (int ni = 0; ni < 4; ni++) {
            int p = ni & 1;
#pragma unroll
            for (int mi = 0; mi < 4; mi++)
#pragma unroll
                for (int r = 0; r < 4; r++)
                    ldsT[wv][p][q * 4 + r][mi * 16 + l] = acc[mi][ni][r];
            asm volatile("s_waitcnt lgkmcnt(0)" ::: "memory");
#pragma unroll
            for (int jj = 0; jj < 4; jj++) {
                f32x4 v = *(const f32x4*)&ldsT[wv][p][jj * 4 + q][l * 4];
                __builtin_nontemporal_store(
                    v, (f32x4*)(C + (size_t)(n0 + ni * 16 + jj * 4 + q) * 8192 + m0 + l * 4));
            }
        }
    }
}

// ---------- aggregation: one wave per node, 16B/lane gathers ----------
// layer 1: h = relu(D^-1/2 A D^-1/2 h0 + b1), F=512 -> lane covers 8 features
__global__ void k_agg1(const bfu* __restrict__ hin, const int2* __restrict__ ep,
                       const int* __restrict__ rs, const float* __restrict__ dinv,
                       const float* __restrict__ bias, bfu* __restrict__ hout) {
    int node = blockIdx.x * 4 + (threadIdx.x >> 6);
    int lane = threadIdx.x & 63;
    int f = lane * 8;
    int s = rs[node], e = rs[node + 1];
    float di = dinv[node];
    float acc[8];
#pragma unroll
    for (int k = 0; k < 8; k++) acc[k] = 0.f;
    const bfu* hf = hin + f;

    int ed = s;
    for (; ed + 2 <= e; ed += 2) {
        int2 p0 = ep[ed], p1 = ep[ed + 1];
        uint4 v0 = *(const uint4*)(hf + (size_t)p0.x * FHID);
        uint4 v1 = *(const uint4*)(hf + (size_t)p1.x * FHID);
        acc8(acc, v0, __int_as_float(p0.y));
        acc8(acc, v1, __int_as_float(p1.y));
    }
    if (ed < e) {
        int2 p0 = ep[ed];
        uint4 v0 = *(const uint4*)(hf + (size_t)p0.x * FHID);
        acc8(acc, v0, __int_as_float(p0.y));
    }
    {   // self-loop
        uint4 vs = *(const uint4*)(hf + (size_t)node * FHID);
        acc8(acc, vs, di);
    }

    f32x4 b0 = *(const f32x4*)(bias + f);
    f32x4 b1v = *(const f32x4*)(bias + f + 4);
    float o[8];
#pragma unroll
    for (int k = 0; k < 4; k++) o[k] = fmaxf(di * acc[k] + b0[k], 0.f);
#pragma unroll
    for (int k = 0; k < 4; k++) o[4 + k] = fmaxf(di * acc[4 + k] + b1v[k], 0.f);
    uint4 ow;
    ow.x = (unsigned int)f2bf(o[0]) | ((unsigned int)f2bf(o[1]) << 16);
    ow.y = (unsigned int)f2bf(o[2]) | ((unsigned int)f2bf(o[3]) << 16);
    ow.z = (unsigned int)f2bf(o[4]) | ((unsigned int)f2bf(o[5]) << 16);
    ow.w = (unsigned int)f2bf(o[6]) | ((unsigned int)f2bf(o[7]) << 16);
    *(uint4*)(hout + (size_t)node * FHID + f) = ow;
}

// layers 2/3 fused: F=256 ([mu | logvar]) -> lane covers 4 features (8B gathers)
__global__ void k_agg2(const bfu* __restrict__ hin, const int2* __restrict__ ep,
                       const int* __restrict__ rs, const float* __restrict__ dinv,
                       const float* __restrict__ bmu, const float* __restrict__ blv,
                       float* __restrict__ out_mu, float* __restrict__ out_lv,
                       float* __restrict__ out_z, bfu* __restrict__ ws_z) {
    int node = blockIdx.x * 4 + (threadIdx.x >> 6);
    int lane = threadIdx.x & 63;
    int f = lane * 4;
    int s = rs[node], e = rs[node + 1];
    float di = dinv[node];
    float acc[4];
#pragma unroll
    for (int k = 0; k < 4; k++) acc[k] = 0.f;
    const bfu* hf = hin + f;

    int ed = s;
    for (; ed + 2 <= e; ed += 2) {
        int2 p0 = ep[ed], p1 = ep[ed + 1];
        uint2 v0 = *(const uint2*)(hf + (size_t)p0.x * 256);
        uint2 v1 = *(const uint2*)(hf + (size_t)p1.x * 256);
        acc4(acc, v0, __int_as_float(p0.y));
        acc4(acc, v1, __int_as_float(p1.y));
    }
    if (ed < e) {
        int2 p0 = ep[ed];
        uint2 v0 = *(const uint2*)(hf + (size_t)p0.x * 256);
        acc4(acc, v0, __int_as_float(p0.y));
    }
    {   // self-loop
        uint2 vs = *(const uint2*)(hf + (size_t)node * 256);
        acc4(acc, vs, di);
    }

    if (f < 128) {
        f32x4 bm = *(const f32x4*)(bmu + f);
        f32x4 fv;
#pragma unroll
        for (int k = 0; k < 4; k++) fv[k] = di * acc[k] + bm[k];
        __builtin_nontemporal_store(fv, (f32x4*)(out_mu + (size_t)node * FLAT + f));
        __builtin_nontemporal_store(fv, (f32x4*)(out_z + (size_t)node * FLAT + f));  // z = mu
        uint2 bw;
        bw.x = (unsigned int)f2bf(fv[0]) | ((unsigned int)f2bf(fv[1]) << 16);
        bw.y = (unsigned int)f2bf(fv[2]) | ((unsigned int)f2bf(fv[3]) << 16);
        *(uint2*)(ws_z + (size_t)node * FLAT + f) = bw;   // reused by decode: keep cached
    } else {
        int fl = f - 128;
        f32x4 bl = *(const f32x4*)(blv + fl);
        f32x4 fv;
#pragma unroll
        for (int k = 0; k < 4; k++) fv[k] = di * acc[k] + bl[k];
        __builtin_nontemporal_store(fv, (f32x4*)(out_lv + (size_t)node * FLAT + fl));
    }
}

extern "C" void kernel_launch(void* const* d_in, const int* in_sizes, int n_in,
                              void* d_out, int out_size, void* d_ws, size_t ws_size,
                              hipStream_t stream) {
    const int*   ei  = (const int*)d_in[0];
    const float* x   = (const float*)d_in[1];
    const float* W1  = (const float*)d_in[2];
    const float* b1  = (const float*)d_in[3];
    const float* Wmu = (const float*)d_in[4];
    const float* bmu = (const float*)d_in[5];
    const float* Wlv = (const float*)d_in[6];
    const float* blv = (const float*)d_in[7];
    float* out = (float*)d_out;

    char* wsb = (char*)d_ws;
    size_t off = 0;
    auto alloc = [&](size_t bytes) -> char* {
        char* p = wsb + off;
        off += (bytes + 255) & ~(size_t)255;
        return p;
    };
    int*   deg       = (int*)alloc(NNODES * 4);
    int*   cursor    = (int*)alloc(NNODES * 4);   // contiguous after deg
    int*   row_start = (int*)alloc((NNODES + 1) * 4);
    float* dinv      = (float*)alloc(NNODES * 4);
    int2*  ep        = (int2*)alloc((size_t)NEDGES * 8);
    bfu*   Bt1       = (bfu*)alloc(512 * 512 * 2);
    bfu*   Bt2       = (bfu*)alloc(256 * 512 * 2);
    bfu*   xb        = (bfu*)alloc((size_t)NNODES * FIN * 2);
    bfu*   h0        = (bfu*)alloc((size_t)NNODES * FHID * 2);
    bfu*   h         = (bfu*)alloc((size_t)NNODES * FHID * 2);
    bfu*   hml       = (bfu*)alloc((size_t)NNODES * 256 * 2);
    bfu*   zb        = (bfu*)alloc((size_t)NNODES * FLAT * 2);

    float* out_mu = out + (size_t)NNODES * NNODES;
    float* out_lv = out_mu + (size_t)NNODES * FLAT;
    float* out_z  = out_lv + (size_t)NNODES * FLAT;

    // graph prep
    k_zero<<<(2 * NNODES + 255) / 256, 256, 0, stream>>>(deg, 2 * NNODES);  // deg + cursor
    k_count<<<NEDGES / 256, 256, 0, stream>>>(ei, deg);
    k_scan<<<1, 256, 0, stream>>>(deg, row_start, dinv);
    k_scatter_prep<<<1024 + 256 + 128 + 4096, 256, 0, stream>>>(
        ei, row_start, cursor, ep, dinv, W1, Wmu, Wlv, x, Bt1, Bt2, xb);

    // layer 1: h0 = x @ W1 ; h = relu(agg(h0) + b1)
    k_gemm_nt<4, 2><<<(8192 / 64) * (512 / 32) / 4, 256, 0, stream>>>(
        xb, Bt1, h0, 8192, 512, 512);
    k_agg1<<<NNODES / 4, 256, 0, stream>>>(h0, ep, row_start, dinv, b1, h);

    // layers 2+3 fused: hml = h @ [Wmu|Wlv]
    k_gemm_nt<2, 2><<<(8192 / 32) * (256 / 32) / 4, 256, 0, stream>>>(
        h, Bt2, hml, 8192, 256, 512);
    k_agg2<<<NNODES / 4, 256, 0, stream>>>(hml, ep, row_start, dinv, bmu, blv,
                                           out_mu, out_lv, out_z, zb);

    // decode: upper-triangle tile-pairs only (8256 wave-tiles / 4 waves per block)
    k_decode_sym<<<8256 / 4, 256, 0, stream>>>(zb, out);
}